// Round 1
// baseline (1519.124 us; speedup 1.0000x reference)
//
#include <hip/hip_runtime.h>
#include <hip/hip_bf16.h>

#define BATCH 8
#define NPTS 4096
#define NS   1024
#define NK   32
#define CIN  128
#define C1PAD 160
#define O1   128
#define O3   256
#define MTOT 32768
#define GN_EPS 1e-5f

typedef float f32x4 __attribute__((ext_vector_type(4)));
typedef short s16x8 __attribute__((ext_vector_type(8)));
typedef short s16x4 __attribute__((ext_vector_type(4)));

static __device__ __forceinline__ unsigned short f2bf(float f){
  unsigned u = __float_as_uint(f);
  u += 0x7fffu + ((u >> 16) & 1u);
  return (unsigned short)(u >> 16);
}
static __device__ __forceinline__ float bf2f(unsigned short h){
  return __uint_as_float(((unsigned)h) << 16);
}
// exact (non-contracted) squared distance matching numpy f32: ((dx*dx)+(dy*dy))+(dz*dz)
static __device__ __forceinline__ float exact_d2(float ax,float ay,float az,float bx,float by,float bz){
  float dx=__fadd_rn(ax,-bx), dy=__fadd_rn(ay,-by), dz=__fadd_rn(az,-bz);
  return __fadd_rn(__fadd_rn(__fmul_rn(dx,dx),__fmul_rn(dy,dy)),__fmul_rn(dz,dz));
}

// ---------------- FPS: one block per batch, exact argmax (first-max-index) ----------------
__global__ __launch_bounds__(512) void k_fps(const float* __restrict__ coords,
                                             int* __restrict__ fps_idx,
                                             float* __restrict__ centers){
  const int b = blockIdx.x;
  const float* cb = coords + (size_t)b*3*NPTS;
  __shared__ float lx[NPTS], ly[NPTS], lz[NPTS];
  __shared__ float sel[3];
  __shared__ unsigned long long red[8];
  const int t = threadIdx.x;
  const int lane = t & 63, wid = t >> 6;
  float px[8],py[8],pz[8],md[8];
  #pragma unroll
  for(int j=0;j<8;++j){
    int p = t + j*512;
    px[j]=cb[p]; py[j]=cb[NPTS+p]; pz[j]=cb[2*NPTS+p];
    lx[p]=px[j]; ly[p]=py[j]; lz[p]=pz[j];
    md[j]=3.4e38f;
  }
  if(t==0){
    sel[0]=cb[0]; sel[1]=cb[NPTS]; sel[2]=cb[2*NPTS];
    fps_idx[b*NS]=0;
    centers[(size_t)(b*3+0)*NS]=cb[0];
    centers[(size_t)(b*3+1)*NS]=cb[NPTS];
    centers[(size_t)(b*3+2)*NS]=cb[2*NPTS];
  }
  __syncthreads();
  for(int it=1; it<NS; ++it){
    const float ax=sel[0], ay=sel[1], az=sel[2];
    float bv=-1.0f;
    #pragma unroll
    for(int j=0;j<8;++j){
      float d = exact_d2(px[j],py[j],pz[j],ax,ay,az);
      md[j]=fminf(md[j],d);
      bv=fmaxf(bv,md[j]);
    }
    #pragma unroll
    for(int m=1;m<64;m<<=1) bv=fmaxf(bv,__shfl_xor(bv,m));
    unsigned ci=0xFFFFFFFFu;
    #pragma unroll
    for(int j=0;j<8;++j){
      unsigned p=(unsigned)(t+j*512);
      ci = (md[j]==bv && p<ci) ? p : ci;
    }
    #pragma unroll
    for(int m=1;m<64;m<<=1){ unsigned o=__shfl_xor(ci,m); ci=(o<ci)?o:ci; }
    if(lane==0) red[wid]=((unsigned long long)__float_as_uint(bv)<<32)|(unsigned long long)(~ci);
    __syncthreads();
    if(wid==0){
      unsigned long long v=(lane<8)?red[lane]:0ull;
      #pragma unroll
      for(int m=1;m<8;m<<=1){ unsigned long long o=__shfl_xor(v,m); v=(o>v)?o:v; }
      if(lane==0){
        unsigned idx=~((unsigned)v);
        sel[0]=lx[idx]; sel[1]=ly[idx]; sel[2]=lz[idx];
        fps_idx[b*NS+it]=(int)idx;
        centers[(size_t)(b*3+0)*NS+it]=lx[idx];
        centers[(size_t)(b*3+1)*NS+it]=ly[idx];
        centers[(size_t)(b*3+2)*NS+it]=lz[idx];
      }
    }
    __syncthreads();
  }
}

// ---------------- misc copies: time_emb slice + style ----------------
__global__ __launch_bounds__(256) void k_misc(const float* __restrict__ time_emb,
                                              const float* __restrict__ style,
                                              float* __restrict__ out_time,
                                              float* __restrict__ out_style){
  int i = blockIdx.x*256 + threadIdx.x;
  int s = i & (NS-1); int bc = i >> 10;
  out_time[i] = time_emb[(size_t)bc*NPTS + s];
  if(i < BATCH*64) out_style[i] = style[i];
}

// ---------------- features (B,128,N) f32 -> point-major rows (B,N,160) bf16, zero-padded ----------------
__global__ __launch_bounds__(256) void k_featT(const float* __restrict__ features,
                                               unsigned short* __restrict__ featT){
  const int b = blockIdx.z, pt = blockIdx.x, ct = blockIdx.y;
  const int t = threadIdx.x;
  const int p0 = pt*64;
  if(ct==2){ // zero channels 128..159
    int r = t>>2, c8 = (t&3)*8;
    s16x8 z = (s16x8){0,0,0,0,0,0,0,0};
    *(s16x8*)&featT[((size_t)b*NPTS + p0 + r)*C1PAD + 128 + c8] = z;
    return;
  }
  const int c0 = ct*64;
  __shared__ float tile[64][65];
  #pragma unroll
  for(int i=0;i<16;++i){
    int c = (t>>6)*16 + i;
    tile[c][t&63] = features[((size_t)b*CIN + c0 + c)*NPTS + p0 + (t&63)];
  }
  __syncthreads();
  #pragma unroll
  for(int i=0;i<16;++i){
    int pl = (t>>6)*16 + i;
    featT[((size_t)b*NPTS + p0 + pl)*C1PAD + c0 + (t&63)] = f2bf(tile[t&63][pl]);
  }
}

// ---------------- weight prep into MFMA fragment order (+ zero stats) ----------------
// Layer1 cols reordered: X1 row = [f0..f127, nc0, nc1, nc2, pad] so W1'[:,j<128]=W1[:,j+3], W1'[:,128+j]=W1[:,j]
__global__ __launch_bounds__(256) void k_wprep(const float* __restrict__ w1,
                                               const float* __restrict__ w2,
                                               const float* __restrict__ w3,
                                               unsigned short* __restrict__ wfrag,
                                               float* __restrict__ stats){
  int task = blockIdx.x*256 + threadIdx.x;
  if(task >= 8704){
    int z = task - 8704;
    if(z < 3*BATCH*8*2) stats[z] = 0.f;
    return;
  }
  int layer, of, cs, ln, ncs; size_t base;
  if(task < 2560){ layer=0; ncs=5; base=0;     int r=task;      of=r/320; r%=320; cs=r>>6; ln=r&63; }
  else if(task < 4608){ layer=1; ncs=4; base=20480; int r=task-2560; of=r>>8; r&=255; cs=r>>6; ln=r&63; }
  else { layer=2; ncs=4; base=36864; int r=task-4608; of=r>>8; r&=255; cs=r>>6; ln=r&63; }
  int o = of*16 + (ln&15);
  s16x8 vals;
  #pragma unroll
  for(int i=0;i<8;++i){
    int c = cs*32 + (ln>>4)*8 + i;
    float v = 0.f;
    if(layer==0){
      if(c<128) v = w1[o*131 + c + 3];
      else if(c<131) v = w1[o*131 + (c-128)];
    } else if(layer==1){
      if(c<128) v = w2[o*128 + c];
    } else {
      if(c<128) v = w3[o*128 + c];
    }
    vals[i]=(short)f2bf(v);
  }
  *(s16x8*)&wfrag[base + ((size_t)(of*ncs + cs)*64 + ln)*8] = vals;
}

// ---------------- ball query: one wave per (b,s) ----------------
__global__ __launch_bounds__(256) void k_ballq(const float* __restrict__ coords,
                                               const float* __restrict__ centers,
                                               int* __restrict__ nidx){
  const int gw = (blockIdx.x*256 + threadIdx.x) >> 6;
  const int lane = threadIdx.x & 63;
  const int wl = (threadIdx.x >> 6);
  const int b = gw >> 10, s = gw & (NS-1);
  const float* cb = coords + (size_t)b*3*NPTS;
  const float cx = centers[(size_t)(b*3+0)*NS+s];
  const float cy = centers[(size_t)(b*3+1)*NS+s];
  const float cz = centers[(size_t)(b*3+2)*NS+s];
  __shared__ int slots[4][NK];
  int cnt = 0;
  for(int base=0; base<NPTS && cnt<NK; base+=64){
    int p = base + lane;
    float d2 = exact_d2(cb[p], cb[NPTS+p], cb[2*NPTS+p], cx,cy,cz);
    bool valid = d2 < 0.0225f;
    unsigned long long mask = __ballot(valid);
    int pos = cnt + (int)__popcll(mask & ((1ull<<lane)-1ull));
    if(valid && pos < NK) slots[wl][pos] = p;
    cnt += (int)__popcll(mask);
  }
  __syncthreads();
  int first = slots[wl][0];
  if(lane < NK){
    int v = (lane < cnt) ? slots[wl][lane] : first;
    nidx[((size_t)b*NS + s)*NK + lane] = v;
  }
}

// ---------------- GEMM1: fused gather + 131->128 MFMA + stats ----------------
__global__ __launch_bounds__(256) void k_gemm1(const unsigned short* __restrict__ featT,
    const int* __restrict__ nidx, const float* __restrict__ coords,
    const float* __restrict__ centers, const unsigned short* __restrict__ wfrag,
    const float* __restrict__ bias, unsigned short* __restrict__ yout,
    float* __restrict__ stats){
  const int b=blockIdx.y, mt=blockIdx.x;
  const int m0=mt*64;
  const int t=threadIdx.x, lane=t&63, wid=t>>6;
  __shared__ unsigned short xs[64][168];
  __shared__ unsigned short ys[64][136];
  __shared__ int pidx[64];
  __shared__ float cenS[2][3];
  __shared__ float wsum[2][8][4];
  if(t<64) pidx[t]=nidx[(size_t)b*MTOT + m0 + t];
  if(t>=64 && t<70){ int u=t-64; int j=u/3, c=u%3; cenS[j][c]=centers[((size_t)b*3+c)*NS + (m0>>5)+j]; }
  __syncthreads();
  for(int q=t;q<1280;q+=256){
    int r=q&63, ch=q>>6;
    *(s16x8*)&xs[r][ch*8] = *(const s16x8*)&featT[((size_t)b*NPTS + pidx[r])*C1PAD + ch*8];
  }
  __syncthreads();
  if(t<64){
    int p=pidx[t]; int sj=t>>5;
    float n0=__fadd_rn(coords[((size_t)b*3+0)*NPTS+p],-cenS[sj][0]);
    float n1=__fadd_rn(coords[((size_t)b*3+1)*NPTS+p],-cenS[sj][1]);
    float n2=__fadd_rn(coords[((size_t)b*3+2)*NPTS+p],-cenS[sj][2]);
    s16x4 nc={(short)f2bf(n0),(short)f2bf(n1),(short)f2bf(n2),0};
    *(s16x4*)&xs[t][128]=nc;
  }
  __syncthreads();
  f32x4 acc[8];
  #pragma unroll
  for(int i=0;i<8;++i) acc[i]=(f32x4){0.f,0.f,0.f,0.f};
  const unsigned short* xrow=&xs[wid*16+(lane&15)][0];
  #pragma unroll
  for(int cs=0;cs<5;++cs){
    s16x8 bfv=*(const s16x8*)&xrow[cs*32+(lane>>4)*8];
    #pragma unroll
    for(int of=0;of<8;++of){
      s16x8 afv=*(const s16x8*)&wfrag[((size_t)(of*5+cs)*64+lane)*8];
      acc[of]=__builtin_amdgcn_mfma_f32_16x16x32_bf16(afv,bfv,acc[of],0,0,0);
    }
  }
  #pragma unroll
  for(int of=0;of<8;++of){
    float ls=0.f,lq=0.f;
    int obase=of*16+((lane>>4)<<2);
    #pragma unroll
    for(int r=0;r<4;++r){
      float y=acc[of][r]+bias[obase+r];
      ys[wid*16+(lane&15)][obase+r]=f2bf(y);
      ls+=y; lq+=y*y;
    }
    #pragma unroll
    for(int m=1;m<64;m<<=1){ ls+=__shfl_xor(ls,m); lq+=__shfl_xor(lq,m); }
    if(lane==0){ wsum[0][of][wid]=ls; wsum[1][of][wid]=lq; }
  }
  __syncthreads();
  for(int q=t;q<1024;q+=256){
    int r=q&63, ch=q>>6;
    *(s16x8*)&yout[((size_t)b*MTOT+m0+r)*O1 + ch*8] = *(const s16x8*)&ys[r][ch*8];
  }
  if(t<8){
    float s1v=wsum[0][t][0]+wsum[0][t][1]+wsum[0][t][2]+wsum[0][t][3];
    float s2v=wsum[1][t][0]+wsum[1][t][1]+wsum[1][t][2]+wsum[1][t][3];
    atomicAdd(&stats[((0*BATCH+b)*8+t)*2+0],s1v);
    atomicAdd(&stats[((0*BATCH+b)*8+t)*2+1],s2v);
  }
}

// ---------------- finalize groupnorm stats -> per-(b,c) scale/shift ----------------
__global__ void k_finalize(const float* __restrict__ stats, const float* __restrict__ gamma,
                           const float* __restrict__ beta, float* __restrict__ ss,
                           int layer, int C){
  int b = blockIdx.x, c = threadIdx.x;
  if(c>=C) return;
  int cpg = C/8;
  int g = c/cpg;
  float cnt = (float)(cpg*NS*NK);
  float s1 = stats[((layer*BATCH+b)*8+g)*2+0];
  float s2 = stats[((layer*BATCH+b)*8+g)*2+1];
  float mu = s1/cnt;
  float var = s2/cnt - mu*mu;
  float sc = gamma[c]*rsqrtf(var+GN_EPS);
  ss[((size_t)b*256+c)*2+0]=sc;
  ss[((size_t)b*256+c)*2+1]=beta[c]-mu*sc;
}

// ---------------- GEMM2/3: norm+SiLU on load, 128->O MFMA + stats. LAYER=1 or 2 ----------------
template<int LAYER>
__global__ __launch_bounds__(256) void k_gemm23(const unsigned short* __restrict__ xin,
    const unsigned short* __restrict__ wfrag, const float* __restrict__ bias,
    const float* __restrict__ gss, unsigned short* __restrict__ yout, float* __restrict__ stats){
  const int b=blockIdx.y, mt=blockIdx.x, ot=blockIdx.z;
  const int OTOT=(LAYER==2)?O3:O1;
  const int m0=mt*64;
  const int t=threadIdx.x, lane=t&63, wid=t>>6;
  __shared__ unsigned short xs[64][136];
  __shared__ unsigned short ys[64][136];
  __shared__ float lsc[CIN], lsh[CIN];
  __shared__ float wsum[2][8][4];
  if(t<CIN){ lsc[t]=gss[((size_t)b*256+t)*2]; lsh[t]=gss[((size_t)b*256+t)*2+1]; }
  __syncthreads();
  for(int q=t;q<1024;q+=256){
    int r=q&63, ch=q>>6;
    s16x8 v = *(const s16x8*)&xin[((size_t)b*MTOT + m0 + r)*CIN + ch*8];
    s16x8 o;
    #pragma unroll
    for(int i=0;i<8;++i){
      int c=ch*8+i;
      float x = bf2f((unsigned short)v[i]);
      x = x*lsc[c] + lsh[c];
      float sg = 1.0f/(1.0f+__expf(-x));
      o[i]=(short)f2bf(x*sg);
    }
    *(s16x8*)&xs[r][ch*8]=o;
  }
  __syncthreads();
  f32x4 acc[8];
  #pragma unroll
  for(int i=0;i<8;++i) acc[i]=(f32x4){0.f,0.f,0.f,0.f};
  const unsigned short* xrow=&xs[wid*16+(lane&15)][0];
  #pragma unroll
  for(int cs=0;cs<4;++cs){
    s16x8 bfv=*(const s16x8*)&xrow[cs*32+(lane>>4)*8];
    #pragma unroll
    for(int of=0;of<8;++of){
      int ofg=ot*8+of;
      s16x8 afv=*(const s16x8*)&wfrag[((size_t)(ofg*4+cs)*64+lane)*8];
      acc[of]=__builtin_amdgcn_mfma_f32_16x16x32_bf16(afv,bfv,acc[of],0,0,0);
    }
  }
  #pragma unroll
  for(int of=0;of<8;++of){
    float ls=0.f,lq=0.f;
    int lobase=of*16+((lane>>4)<<2);
    int obase=ot*128+lobase;
    #pragma unroll
    for(int r=0;r<4;++r){
      float y=acc[of][r]+bias[obase+r];
      ys[wid*16+(lane&15)][lobase+r]=f2bf(y);
      ls+=y; lq+=y*y;
    }
    #pragma unroll
    for(int m=1;m<64;m<<=1){ ls+=__shfl_xor(ls,m); lq+=__shfl_xor(lq,m); }
    if(lane==0){ wsum[0][of][wid]=ls; wsum[1][of][wid]=lq; }
  }
  __syncthreads();
  for(int q=t;q<1024;q+=256){
    int r=q&63, ch=q>>6;
    *(s16x8*)&yout[((size_t)b*MTOT+m0+r)*OTOT + ot*128 + ch*8] = *(const s16x8*)&ys[r][ch*8];
  }
  if(t<8){
    float s1v=wsum[0][t][0]+wsum[0][t][1]+wsum[0][t][2]+wsum[0][t][3];
    float s2v=wsum[1][t][0]+wsum[1][t][1]+wsum[1][t][2]+wsum[1][t][3];
    int g = (LAYER==2) ? (ot*4 + (t>>1)) : t;
    atomicAdd(&stats[((LAYER*BATCH+b)*8+g)*2+0],s1v);
    atomicAdd(&stats[((LAYER*BATCH+b)*8+g)*2+1],s2v);
  }
}

// ---------------- final: norm3+SiLU + max over K, transposed coalesced writes ----------------
__global__ __launch_bounds__(256) void k_maxpool(const unsigned short* __restrict__ y3,
    const float* __restrict__ gss, float* __restrict__ out){
  const int b = blockIdx.z, st = blockIdx.x, ot = blockIdx.y;
  const int s0 = st*16, o0 = ot*64;
  const int t=threadIdx.x, lane=t&63, wid=t>>6;
  __shared__ float mx[16][68];
  __shared__ float lsc[64], lsh[64];
  if(t<64){ lsc[t]=gss[((size_t)b*256+o0+t)*2]; lsh[t]=gss[((size_t)b*256+o0+t)*2+1]; }
  __syncthreads();
  for(int si=wid; si<16; si+=4){
    int s = s0+si;
    float m = -3.4e38f;
    float sc=lsc[lane], sh=lsh[lane];
    for(int k=0;k<NK;++k){
      float v = bf2f(y3[((size_t)b*MTOT + s*NK + k)*O3 + o0 + lane]);
      v = v*sc + sh;
      float sg = 1.0f/(1.0f+__expf(-v));
      v = v*sg;
      m = fmaxf(m,v);
    }
    mx[si][lane] = m;
  }
  __syncthreads();
  {
    int ol = t>>2, sl = (t&3)*4;
    float4 v = make_float4(mx[sl][ol], mx[sl+1][ol], mx[sl+2][ol], mx[sl+3][ol]);
    *(float4*)&out[((size_t)(b*O3 + o0+ol))*NS + s0 + sl] = v;
  }
}

extern "C" void kernel_launch(void* const* d_in, const int* in_sizes, int n_in,
                              void* d_out, int out_size, void* d_ws, size_t ws_size,
                              hipStream_t stream){
  const float* features=(const float*)d_in[0];
  const float* coords=(const float*)d_in[1];
  const float* time_emb=(const float*)d_in[2];
  const float* style=(const float*)d_in[3];
  const float* w1=(const float*)d_in[4];
  const float* b1=(const float*)d_in[5];
  const float* g1=(const float*)d_in[6];
  const float* be1=(const float*)d_in[7];
  const float* w2=(const float*)d_in[8];
  const float* b2=(const float*)d_in[9];
  const float* g2=(const float*)d_in[10];
  const float* be2=(const float*)d_in[11];
  const float* w3=(const float*)d_in[12];
  const float* b3=(const float*)d_in[13];
  const float* g3=(const float*)d_in[14];
  const float* be3=(const float*)d_in[15];

  float* out0=(float*)d_out;
  float* out_centers=out0 + (size_t)BATCH*O3*NS;
  float* out_time=out_centers + (size_t)BATCH*3*NS;
  float* out_style=out_time + (size_t)BATCH*64*NS;

  char* ws=(char*)d_ws;
  int* fpsidx=(int*)(ws);
  int* nidx=(int*)(ws + 131072);
  unsigned short* featT=(unsigned short*)(ws + 1179648);
  unsigned short* wfrag=(unsigned short*)(ws + 11796480);
  float* stats=(float*)(ws + 11939840);
  float* ssb=(float*)(ws + 11943936);
  unsigned short* y3=(unsigned short*)(ws + 12582912);   // 128 MB region; y1 aliases first half
  unsigned short* y1=y3;
  unsigned short* y2=(unsigned short*)(ws + 146800640);  // 64 MB

  k_fps<<<BATCH,512,0,stream>>>(coords,fpsidx,out_centers);
  k_misc<<<2048,256,0,stream>>>(time_emb,style,out_time,out_style);
  k_featT<<<dim3(64,3,BATCH),256,0,stream>>>(features,featT);
  k_wprep<<<36,256,0,stream>>>(w1,w2,w3,wfrag,stats);
  k_ballq<<<2048,256,0,stream>>>(coords,out_centers,nidx);
  k_gemm1<<<dim3(512,BATCH),256,0,stream>>>(featT,nidx,coords,out_centers,wfrag,b1,y1,stats);
  k_finalize<<<BATCH,128,0,stream>>>(stats,g1,be1,ssb,0,128);
  k_gemm23<1><<<dim3(512,BATCH,1),256,0,stream>>>(y1,wfrag+20480,b2,ssb,y2,stats);
  k_finalize<<<BATCH,128,0,stream>>>(stats,g2,be2,ssb+4096,1,128);
  k_gemm23<2><<<dim3(512,BATCH,2),256,0,stream>>>(y2,wfrag+36864,b3,ssb+4096,y3,stats);
  k_finalize<<<BATCH,256,0,stream>>>(stats,g3,be3,ssb+8192,2,256);
  k_maxpool<<<dim3(64,4,BATCH),256,0,stream>>>(y3,ssb+8192,out0);
}

// Round 2
// 1323.787 us; speedup vs baseline: 1.1476x; 1.1476x over previous
//
#include <hip/hip_runtime.h>
#include <hip/hip_bf16.h>

#define BATCH 8
#define NPTS 4096
#define NS   1024
#define NK   32
#define CIN  128
#define C1PAD 160
#define O1   128
#define O3   256
#define MTOT 32768
#define GN_EPS 1e-5f

typedef float f32x4 __attribute__((ext_vector_type(4)));
typedef short s16x8 __attribute__((ext_vector_type(8)));
typedef short s16x4 __attribute__((ext_vector_type(4)));

static __device__ __forceinline__ unsigned short f2bf(float f){
  unsigned u = __float_as_uint(f);
  u += 0x7fffu + ((u >> 16) & 1u);
  return (unsigned short)(u >> 16);
}
static __device__ __forceinline__ float bf2f(unsigned short h){
  return __uint_as_float(((unsigned)h) << 16);
}
// exact (non-contracted) squared distance matching numpy f32: ((dx*dx)+(dy*dy))+(dz*dz)
static __device__ __forceinline__ float exact_d2(float ax,float ay,float az,float bx,float by,float bz){
  float dx=__fadd_rn(ax,-bx), dy=__fadd_rn(ay,-by), dz=__fadd_rn(az,-bz);
  return __fadd_rn(__fadd_rn(__fmul_rn(dx,dx),__fmul_rn(dy,dy)),__fmul_rn(dz,dz));
}

// block-range layout of the fused kernel
#define FPS_BLOCKS 8
#define FT_BASE    8
#define FT_BLOCKS  128
#define ZP_BASE    136
#define ZP_BLOCKS  8
#define WP_BASE    144
#define WP_BLOCKS  18
#define MS_BASE    162
#define MS_BLOCKS  32
#define TOTAL_BLOCKS 194

// ---------------- fused: FPS (blocks 0..7) + all prep on idle CUs ----------------
__global__ __launch_bounds__(512) void k_fused(
    const float* __restrict__ coords, const float* __restrict__ features,
    const float* __restrict__ time_emb, const float* __restrict__ style,
    const float* __restrict__ w1, const float* __restrict__ w2, const float* __restrict__ w3,
    float* __restrict__ centers, float* __restrict__ out_time, float* __restrict__ out_style,
    unsigned short* __restrict__ featT, unsigned short* __restrict__ wfrag,
    float* __restrict__ stats){
  union U {
    struct { float lx[NPTS]; float ly[NPTS]; float lz[NPTS]; unsigned long long red[2][8]; } fps;
    float tile[64][65];
  };
  __shared__ U sm;
  const int blk = blockIdx.x;
  const int t = threadIdx.x;

  if(blk < FPS_BLOCKS){
    // ---- furthest point sampling, one block per batch ----
    const int b = blk;
    const float* cb = coords + (size_t)b*3*NPTS;
    const int lane = t & 63, wid = t >> 6;
    float px[8],py[8],pz[8],md[8];
    #pragma unroll
    for(int j=0;j<8;++j){
      int p = t + j*512;
      px[j]=cb[p]; py[j]=cb[NPTS+p]; pz[j]=cb[2*NPTS+p];
      sm.fps.lx[p]=px[j]; sm.fps.ly[p]=py[j]; sm.fps.lz[p]=pz[j];
      md[j]=3.4e38f;
    }
    if(t==0){
      centers[(size_t)(b*3+0)*NS]=cb[0];
      centers[(size_t)(b*3+1)*NS]=cb[NPTS];
      centers[(size_t)(b*3+2)*NS]=cb[2*NPTS];
    }
    __syncthreads();
    float ax=sm.fps.lx[0], ay=sm.fps.ly[0], az=sm.fps.lz[0];
    for(int it=1; it<NS; ++it){
      unsigned long long best=0ull;
      #pragma unroll
      for(int j=0;j<8;++j){
        float d = exact_d2(px[j],py[j],pz[j],ax,ay,az);
        md[j]=fminf(md[j],d);
        unsigned long long cand = ((unsigned long long)__float_as_uint(md[j])<<32)
                                  | (unsigned)~(t + j*512);
        best = (cand>best) ? cand : best;
      }
      #pragma unroll
      for(int m=1;m<64;m<<=1){
        unsigned long long o = __shfl_xor(best, m);
        best = (o>best) ? o : best;
      }
      if(lane==0) sm.fps.red[it&1][wid]=best;
      __syncthreads();   // single barrier per iteration (red[] double-buffered)
      unsigned long long w = sm.fps.red[it&1][0];
      #pragma unroll
      for(int i=1;i<8;++i){ unsigned long long o=sm.fps.red[it&1][i]; w=(o>w)?o:w; }
      unsigned idx = ~(unsigned)w;
      ax=sm.fps.lx[idx]; ay=sm.fps.ly[idx]; az=sm.fps.lz[idx];
      if(t==0){
        centers[(size_t)(b*3+0)*NS+it]=ax;
        centers[(size_t)(b*3+1)*NS+it]=ay;
        centers[(size_t)(b*3+2)*NS+it]=az;
      }
    }
    return;
  }

  if(blk < ZP_BASE){
    // ---- features (B,128,N) f32 -> point-major (B,N,160) bf16 (channels 0..127) ----
    const int pb = blk - FT_BASE;
    for(int j=0;j<8;++j){
      int tid = pb*8 + j;
      int bb = tid>>7, r = tid&127, ct = r>>6, pt = r&63;
      int c0 = ct*64, p0 = pt*64;
      #pragma unroll
      for(int i=0;i<8;++i){
        int c = (t>>6)*8 + i;
        sm.tile[c][t&63] = features[((size_t)bb*CIN + c0 + c)*NPTS + p0 + (t&63)];
      }
      __syncthreads();
      #pragma unroll
      for(int i=0;i<8;++i){
        int pl = (t>>6)*8 + i;
        featT[((size_t)bb*NPTS + p0 + pl)*C1PAD + c0 + (t&63)] = f2bf(sm.tile[t&63][pl]);
      }
      __syncthreads();
    }
    return;
  }

  if(blk < WP_BASE){
    // ---- zero featT channels 128..159 ----
    const int zb = blk - ZP_BASE;
    s16x8 z = (s16x8){0,0,0,0,0,0,0,0};
    #pragma unroll 4
    for(int i=0;i<32;++i){
      int q = zb*16384 + i*512 + t;
      int bb = q>>14, rem = q&16383, r = rem>>2, c8 = (rem&3)*8;
      *(s16x8*)&featT[((size_t)bb*NPTS + r)*C1PAD + 128 + c8] = z;
    }
    return;
  }

  if(blk < MS_BASE){
    // ---- weight prep into MFMA fragment order (+ zero stats) ----
    int task = (blk - WP_BASE)*512 + t;
    if(task >= 9088) return;
    if(task >= 8704){
      int z = task - 8704;
      if(z < 3*BATCH*8*2) stats[z] = 0.f;
      return;
    }
    int layer, of, cs, ln, ncs; size_t base;
    if(task < 2560){ layer=0; ncs=5; base=0;     int r=task;      of=r/320; r%=320; cs=r>>6; ln=r&63; }
    else if(task < 4608){ layer=1; ncs=4; base=20480; int r=task-2560; of=r>>8; r&=255; cs=r>>6; ln=r&63; }
    else { layer=2; ncs=4; base=36864; int r=task-4608; of=r>>8; r&=255; cs=r>>6; ln=r&63; }
    int o = of*16 + (ln&15);
    s16x8 vals;
    #pragma unroll
    for(int i=0;i<8;++i){
      int c = cs*32 + (ln>>4)*8 + i;
      float v = 0.f;
      if(layer==0){
        if(c<128) v = w1[o*131 + c + 3];
        else if(c<131) v = w1[o*131 + (c-128)];
      } else if(layer==1){
        if(c<128) v = w2[o*128 + c];
      } else {
        if(c<128) v = w3[o*128 + c];
      }
      vals[i]=(short)f2bf(v);
    }
    *(s16x8*)&wfrag[base + ((size_t)(of*ncs + cs)*64 + ln)*8] = vals;
    return;
  }

  {
    // ---- time_emb slice (float4) + style copy ----
    const int mb = blk - MS_BASE;
    #pragma unroll 4
    for(int i=0;i<8;++i){
      int q = mb*4096 + i*512 + t;
      int f = q*4;
      int bb = f>>16, c = (f>>10)&63, s = f&1023;
      *(float4*)&out_time[f] = *(const float4*)&time_emb[((size_t)bb*64 + c)*NPTS + s];
    }
    if(mb==0) out_style[t] = style[t];
  }
}

// ---------------- ball query: one wave per (b,s) ----------------
__global__ __launch_bounds__(256) void k_ballq(const float* __restrict__ coords,
                                               const float* __restrict__ centers,
                                               int* __restrict__ nidx){
  const int gw = (blockIdx.x*256 + threadIdx.x) >> 6;
  const int lane = threadIdx.x & 63;
  const int wl = (threadIdx.x >> 6);
  const int b = gw >> 10, s = gw & (NS-1);
  const float* cb = coords + (size_t)b*3*NPTS;
  const float cx = centers[(size_t)(b*3+0)*NS+s];
  const float cy = centers[(size_t)(b*3+1)*NS+s];
  const float cz = centers[(size_t)(b*3+2)*NS+s];
  __shared__ int slots[4][NK];
  int cnt = 0;
  for(int base=0; base<NPTS && cnt<NK; base+=64){
    int p = base + lane;
    float d2 = exact_d2(cb[p], cb[NPTS+p], cb[2*NPTS+p], cx,cy,cz);
    bool valid = d2 < 0.0225f;
    unsigned long long mask = __ballot(valid);
    int pos = cnt + (int)__popcll(mask & ((1ull<<lane)-1ull));
    if(valid && pos < NK) slots[wl][pos] = p;
    cnt += (int)__popcll(mask);
  }
  __syncthreads();
  int first = slots[wl][0];
  if(lane < NK){
    int v = (lane < cnt) ? slots[wl][lane] : first;
    nidx[((size_t)b*NS + s)*NK + lane] = v;
  }
}

// ---------------- GEMM1: fused gather + 131->128 MFMA + stats ----------------
__global__ __launch_bounds__(256) void k_gemm1(const unsigned short* __restrict__ featT,
    const int* __restrict__ nidx, const float* __restrict__ coords,
    const float* __restrict__ centers, const unsigned short* __restrict__ wfrag,
    const float* __restrict__ bias, unsigned short* __restrict__ yout,
    float* __restrict__ stats){
  const int b=blockIdx.y, mt=blockIdx.x;
  const int m0=mt*64;
  const int t=threadIdx.x, lane=t&63, wid=t>>6;
  __shared__ unsigned short xs[64][168];
  __shared__ unsigned short ys[64][136];
  __shared__ int pidx[64];
  __shared__ float cenS[2][3];
  __shared__ float wsum[2][8][4];
  if(t<64) pidx[t]=nidx[(size_t)b*MTOT + m0 + t];
  if(t>=64 && t<70){ int u=t-64; int j=u/3, c=u%3; cenS[j][c]=centers[((size_t)b*3+c)*NS + (m0>>5)+j]; }
  __syncthreads();
  for(int q=t;q<1280;q+=256){
    int r=q&63, ch=q>>6;
    *(s16x8*)&xs[r][ch*8] = *(const s16x8*)&featT[((size_t)b*NPTS + pidx[r])*C1PAD + ch*8];
  }
  __syncthreads();
  if(t<64){
    int p=pidx[t]; int sj=t>>5;
    float n0=__fadd_rn(coords[((size_t)b*3+0)*NPTS+p],-cenS[sj][0]);
    float n1=__fadd_rn(coords[((size_t)b*3+1)*NPTS+p],-cenS[sj][1]);
    float n2=__fadd_rn(coords[((size_t)b*3+2)*NPTS+p],-cenS[sj][2]);
    s16x4 nc={(short)f2bf(n0),(short)f2bf(n1),(short)f2bf(n2),0};
    *(s16x4*)&xs[t][128]=nc;
  }
  __syncthreads();
  f32x4 acc[8];
  #pragma unroll
  for(int i=0;i<8;++i) acc[i]=(f32x4){0.f,0.f,0.f,0.f};
  const unsigned short* xrow=&xs[wid*16+(lane&15)][0];
  #pragma unroll
  for(int cs=0;cs<5;++cs){
    s16x8 bfv=*(const s16x8*)&xrow[cs*32+(lane>>4)*8];
    #pragma unroll
    for(int of=0;of<8;++of){
      s16x8 afv=*(const s16x8*)&wfrag[((size_t)(of*5+cs)*64+lane)*8];
      acc[of]=__builtin_amdgcn_mfma_f32_16x16x32_bf16(afv,bfv,acc[of],0,0,0);
    }
  }
  #pragma unroll
  for(int of=0;of<8;++of){
    float ls=0.f,lq=0.f;
    int obase=of*16+((lane>>4)<<2);
    #pragma unroll
    for(int r=0;r<4;++r){
      float y=acc[of][r]+bias[obase+r];
      ys[wid*16+(lane&15)][obase+r]=f2bf(y);
      ls+=y; lq+=y*y;
    }
    #pragma unroll
    for(int m=1;m<64;m<<=1){ ls+=__shfl_xor(ls,m); lq+=__shfl_xor(lq,m); }
    if(lane==0){ wsum[0][of][wid]=ls; wsum[1][of][wid]=lq; }
  }
  __syncthreads();
  for(int q=t;q<1024;q+=256){
    int r=q&63, ch=q>>6;
    *(s16x8*)&yout[((size_t)b*MTOT+m0+r)*O1 + ch*8] = *(const s16x8*)&ys[r][ch*8];
  }
  if(t<8){
    float s1v=wsum[0][t][0]+wsum[0][t][1]+wsum[0][t][2]+wsum[0][t][3];
    float s2v=wsum[1][t][0]+wsum[1][t][1]+wsum[1][t][2]+wsum[1][t][3];
    atomicAdd(&stats[((0*BATCH+b)*8+t)*2+0],s1v);
    atomicAdd(&stats[((0*BATCH+b)*8+t)*2+1],s2v);
  }
}

// ---------------- GEMM2/3: stats->norm+SiLU on load, 128->O MFMA + stats ----------------
template<int LAYER>
__global__ __launch_bounds__(256) void k_gemm23(const unsigned short* __restrict__ xin,
    const unsigned short* __restrict__ wfrag, const float* __restrict__ bias,
    const float* __restrict__ stats, const float* __restrict__ gprev,
    const float* __restrict__ beprev, unsigned short* __restrict__ yout,
    float* __restrict__ statsOut){
  const int b=blockIdx.y, mt=blockIdx.x, ot=blockIdx.z;
  const int OTOT=(LAYER==2)?O3:O1;
  const int m0=mt*64;
  const int t=threadIdx.x, lane=t&63, wid=t>>6;
  __shared__ unsigned short xs[64][136];
  __shared__ unsigned short ys[64][136];
  __shared__ float lsc[CIN], lsh[CIN];
  __shared__ float wsum[2][8][4];
  if(t<CIN){
    int g = t>>4;                               // input layer cpg = 16
    const float cnt = 16.0f*NS*NK;
    float s1=stats[(((LAYER-1)*BATCH+b)*8+g)*2+0];
    float s2=stats[(((LAYER-1)*BATCH+b)*8+g)*2+1];
    float mu=s1/cnt, var=s2/cnt-mu*mu;
    float sc=gprev[t]*rsqrtf(var+GN_EPS);
    lsc[t]=sc; lsh[t]=beprev[t]-mu*sc;
  }
  __syncthreads();
  for(int q=t;q<1024;q+=256){
    int r=q&63, ch=q>>6;
    s16x8 v = *(const s16x8*)&xin[((size_t)b*MTOT + m0 + r)*CIN + ch*8];
    s16x8 o;
    #pragma unroll
    for(int i=0;i<8;++i){
      int c=ch*8+i;
      float x = bf2f((unsigned short)v[i]);
      x = x*lsc[c] + lsh[c];
      float sg = 1.0f/(1.0f+__expf(-x));
      o[i]=(short)f2bf(x*sg);
    }
    *(s16x8*)&xs[r][ch*8]=o;
  }
  __syncthreads();
  f32x4 acc[8];
  #pragma unroll
  for(int i=0;i<8;++i) acc[i]=(f32x4){0.f,0.f,0.f,0.f};
  const unsigned short* xrow=&xs[wid*16+(lane&15)][0];
  #pragma unroll
  for(int cs=0;cs<4;++cs){
    s16x8 bfv=*(const s16x8*)&xrow[cs*32+(lane>>4)*8];
    #pragma unroll
    for(int of=0;of<8;++of){
      int ofg=ot*8+of;
      s16x8 afv=*(const s16x8*)&wfrag[((size_t)(ofg*4+cs)*64+lane)*8];
      acc[of]=__builtin_amdgcn_mfma_f32_16x16x32_bf16(afv,bfv,acc[of],0,0,0);
    }
  }
  #pragma unroll
  for(int of=0;of<8;++of){
    float ls=0.f,lq=0.f;
    int lobase=of*16+((lane>>4)<<2);
    int obase=ot*128+lobase;
    #pragma unroll
    for(int r=0;r<4;++r){
      float y=acc[of][r]+bias[obase+r];
      ys[wid*16+(lane&15)][lobase+r]=f2bf(y);
      ls+=y; lq+=y*y;
    }
    #pragma unroll
    for(int m=1;m<64;m<<=1){ ls+=__shfl_xor(ls,m); lq+=__shfl_xor(lq,m); }
    if(lane==0){ wsum[0][of][wid]=ls; wsum[1][of][wid]=lq; }
  }
  __syncthreads();
  for(int q=t;q<1024;q+=256){
    int r=q&63, ch=q>>6;
    *(s16x8*)&yout[((size_t)b*MTOT+m0+r)*OTOT + ot*128 + ch*8] = *(const s16x8*)&ys[r][ch*8];
  }
  if(t<8){
    float s1v=wsum[0][t][0]+wsum[0][t][1]+wsum[0][t][2]+wsum[0][t][3];
    float s2v=wsum[1][t][0]+wsum[1][t][1]+wsum[1][t][2]+wsum[1][t][3];
    int g = (LAYER==2) ? (ot*4 + (t>>1)) : t;
    atomicAdd(&statsOut[((LAYER*BATCH+b)*8+g)*2+0],s1v);
    atomicAdd(&statsOut[((LAYER*BATCH+b)*8+g)*2+1],s2v);
  }
}

// ---------------- final: stats->norm3+SiLU + max over K, transposed coalesced writes ----------------
__global__ __launch_bounds__(256) void k_maxpool(const unsigned short* __restrict__ y3,
    const float* __restrict__ stats, const float* __restrict__ g3,
    const float* __restrict__ be3, float* __restrict__ out){
  const int b = blockIdx.z, st = blockIdx.x, ot = blockIdx.y;
  const int s0 = st*16, o0 = ot*64;
  const int t=threadIdx.x, lane=t&63, wid=t>>6;
  __shared__ float mx[16][68];
  __shared__ float lsc[64], lsh[64];
  if(t<64){
    int c=o0+t, g=c>>5;                         // layer3 cpg = 32
    const float cnt = 32.0f*NS*NK;
    float s1=stats[((2*BATCH+b)*8+g)*2+0];
    float s2=stats[((2*BATCH+b)*8+g)*2+1];
    float mu=s1/cnt, var=s2/cnt-mu*mu;
    float sc=g3[c]*rsqrtf(var+GN_EPS);
    lsc[t]=sc; lsh[t]=be3[c]-mu*sc;
  }
  __syncthreads();
  for(int si=wid; si<16; si+=4){
    int s = s0+si;
    float m = -3.4e38f;
    float sc=lsc[lane], sh=lsh[lane];
    for(int k=0;k<NK;++k){
      float v = bf2f(y3[((size_t)b*MTOT + s*NK + k)*O3 + o0 + lane]);
      v = v*sc + sh;
      float sg = 1.0f/(1.0f+__expf(-v));
      v = v*sg;
      m = fmaxf(m,v);
    }
    mx[si][lane] = m;
  }
  __syncthreads();
  {
    int ol = t>>2, sl = (t&3)*4;
    float4 v = make_float4(mx[sl][ol], mx[sl+1][ol], mx[sl+2][ol], mx[sl+3][ol]);
    *(float4*)&out[((size_t)(b*O3 + o0+ol))*NS + s0 + sl] = v;
  }
}

extern "C" void kernel_launch(void* const* d_in, const int* in_sizes, int n_in,
                              void* d_out, int out_size, void* d_ws, size_t ws_size,
                              hipStream_t stream){
  const float* features=(const float*)d_in[0];
  const float* coords=(const float*)d_in[1];
  const float* time_emb=(const float*)d_in[2];
  const float* style=(const float*)d_in[3];
  const float* w1=(const float*)d_in[4];
  const float* b1=(const float*)d_in[5];
  const float* g1=(const float*)d_in[6];
  const float* be1=(const float*)d_in[7];
  const float* w2=(const float*)d_in[8];
  const float* b2=(const float*)d_in[9];
  const float* g2=(const float*)d_in[10];
  const float* be2=(const float*)d_in[11];
  const float* w3=(const float*)d_in[12];
  const float* b3=(const float*)d_in[13];
  const float* g3=(const float*)d_in[14];
  const float* be3=(const float*)d_in[15];

  float* out0=(float*)d_out;
  float* out_centers=out0 + (size_t)BATCH*O3*NS;
  float* out_time=out_centers + (size_t)BATCH*3*NS;
  float* out_style=out_time + (size_t)BATCH*64*NS;

  char* ws=(char*)d_ws;
  int* nidx=(int*)(ws + 131072);
  unsigned short* featT=(unsigned short*)(ws + 1179648);
  unsigned short* wfrag=(unsigned short*)(ws + 11796480);
  float* stats=(float*)(ws + 11939840);
  unsigned short* y3=(unsigned short*)(ws + 12582912);   // 128 MB region; y1 aliases first half
  unsigned short* y1=y3;
  unsigned short* y2=(unsigned short*)(ws + 146800640);  // 64 MB

  k_fused<<<TOTAL_BLOCKS,512,0,stream>>>(coords,features,time_emb,style,w1,w2,w3,
                                         out_centers,out_time,out_style,featT,wfrag,stats);
  k_ballq<<<2048,256,0,stream>>>(coords,out_centers,nidx);
  k_gemm1<<<dim3(512,BATCH),256,0,stream>>>(featT,nidx,coords,out_centers,wfrag,b1,y1,stats);
  k_gemm23<1><<<dim3(512,BATCH,1),256,0,stream>>>(y1,wfrag+20480,b2,stats,g1,be1,y2,stats);
  k_gemm23<2><<<dim3(512,BATCH,2),256,0,stream>>>(y2,wfrag+36864,b3,stats,g2,be2,y3,stats);
  k_maxpool<<<dim3(64,4,BATCH),256,0,stream>>>(y3,stats,g3,be3,out0);
}

// Round 3
// 1185.828 us; speedup vs baseline: 1.2811x; 1.1163x over previous
//
#include <hip/hip_runtime.h>
#include <hip/hip_bf16.h>

#define BATCH 8
#define NPTS 4096
#define NS   1024
#define NK   32
#define CIN  128
#define C1PAD 160
#define O1   128
#define O3   256
#define MTOT 32768
#define GN_EPS 1e-5f

typedef float f32x4 __attribute__((ext_vector_type(4)));
typedef short s16x8 __attribute__((ext_vector_type(8)));
typedef short s16x4 __attribute__((ext_vector_type(4)));

static __device__ __forceinline__ unsigned short f2bf(float f){
  unsigned u = __float_as_uint(f);
  u += 0x7fffu + ((u >> 16) & 1u);
  return (unsigned short)(u >> 16);
}
static __device__ __forceinline__ float bf2f(unsigned short h){
  return __uint_as_float(((unsigned)h) << 16);
}
// exact (non-contracted) squared distance matching numpy f32: ((dx*dx)+(dy*dy))+(dz*dz)
static __device__ __forceinline__ float exact_d2(float ax,float ay,float az,float bx,float by,float bz){
  float dx=__fadd_rn(ax,-bx), dy=__fadd_rn(ay,-by), dz=__fadd_rn(az,-bz);
  return __fadd_rn(__fadd_rn(__fmul_rn(dx,dx),__fmul_rn(dy,dy)),__fmul_rn(dz,dz));
}
// wave-wide u32 max via DPP (distances >= 0 so f32 max == u32 max on bits)
static __device__ __forceinline__ unsigned wave_umax_dpp(unsigned v){
  unsigned o;
  o = (unsigned)__builtin_amdgcn_update_dpp(0, (int)v, 0x111, 0xf, 0xf, true); v = (o>v)?o:v; // row_shr:1
  o = (unsigned)__builtin_amdgcn_update_dpp(0, (int)v, 0x112, 0xf, 0xf, true); v = (o>v)?o:v; // row_shr:2
  o = (unsigned)__builtin_amdgcn_update_dpp(0, (int)v, 0x114, 0xf, 0xf, true); v = (o>v)?o:v; // row_shr:4
  o = (unsigned)__builtin_amdgcn_update_dpp(0, (int)v, 0x118, 0xf, 0xf, true); v = (o>v)?o:v; // row_shr:8
  o = (unsigned)__builtin_amdgcn_update_dpp(0, (int)v, 0x142, 0xf, 0xf, true); v = (o>v)?o:v; // row_bcast:15
  o = (unsigned)__builtin_amdgcn_update_dpp(0, (int)v, 0x143, 0xf, 0xf, true); v = (o>v)?o:v; // row_bcast:31
  return v;  // lane 63 holds the wave max
}

// block-range layout of the fused kernel
#define FPS_BLOCKS 8
#define FT_BASE    8
#define FT_BLOCKS  128
#define ZP_BASE    136
#define ZP_BLOCKS  8
#define WP_BASE    144
#define WP_BLOCKS  18
#define MS_BASE    162
#define MS_BLOCKS  32
#define TOTAL_BLOCKS 194

// ---------------- fused: FPS (blocks 0..7) + all prep on idle CUs ----------------
__global__ __launch_bounds__(512) void k_fused(
    const float* __restrict__ coords, const float* __restrict__ features,
    const float* __restrict__ time_emb, const float* __restrict__ style,
    const float* __restrict__ w1, const float* __restrict__ w2, const float* __restrict__ w3,
    float* __restrict__ centers, float* __restrict__ out_time, float* __restrict__ out_style,
    unsigned short* __restrict__ featT, unsigned short* __restrict__ wfrag,
    float* __restrict__ stats){
  union U {
    struct { float lx[NPTS]; float ly[NPTS]; float lz[NPTS]; unsigned long long red[2][8]; } fps;
    float tile[64][65];
  };
  __shared__ U sm;
  const int blk = blockIdx.x;
  const int t = threadIdx.x;

  if(blk < FPS_BLOCKS){
    // ---- furthest point sampling, one block per batch ----
    const int b = blk;
    const float* cb = coords + (size_t)b*3*NPTS;
    const int lane = t & 63, wid = t >> 6;
    float px[8],py[8],pz[8],md[8];
    #pragma unroll
    for(int j=0;j<8;++j){
      int p = t + j*512;
      px[j]=cb[p]; py[j]=cb[NPTS+p]; pz[j]=cb[2*NPTS+p];
      sm.fps.lx[p]=px[j]; sm.fps.ly[p]=py[j]; sm.fps.lz[p]=pz[j];
      md[j]=3.4e38f;
    }
    if(t==0){
      centers[(size_t)(b*3+0)*NS]=cb[0];
      centers[(size_t)(b*3+1)*NS]=cb[NPTS];
      centers[(size_t)(b*3+2)*NS]=cb[2*NPTS];
    }
    __syncthreads();
    float ax=sm.fps.lx[0], ay=sm.fps.ly[0], az=sm.fps.lz[0];
    for(int it=1; it<NS; ++it){
      float bmax = -1.0f;
      #pragma unroll
      for(int j=0;j<8;++j){
        float d = exact_d2(px[j],py[j],pz[j],ax,ay,az);
        md[j]=fminf(md[j],d);
        bmax=fmaxf(bmax,md[j]);
      }
      // wave max via DPP (6 VALU ops), broadcast from lane 63 through SGPR
      unsigned bvb = (unsigned)__builtin_amdgcn_readlane((int)wave_umax_dpp(__float_as_uint(bmax)), 63);
      // wave argmax index: 8 ballots, descending j so smallest global idx wins
      int widx = 0;
      #pragma unroll
      for(int j=7;j>=0;--j){
        unsigned long long mj = __ballot(__float_as_uint(md[j])==bvb);
        int cand = j*512 + (wid<<6) + (__ffsll(mj)-1);
        widx = mj ? cand : widx;
      }
      if(lane==0) sm.fps.red[it&1][wid] = ((unsigned long long)bvb<<32) | (unsigned)~widx;
      __syncthreads();   // single barrier per iteration (red[] double-buffered)
      const unsigned long long* rr = sm.fps.red[it&1];
      unsigned long long w01 = rr[0]>rr[1]?rr[0]:rr[1];
      unsigned long long w23 = rr[2]>rr[3]?rr[2]:rr[3];
      unsigned long long w45 = rr[4]>rr[5]?rr[4]:rr[5];
      unsigned long long w67 = rr[6]>rr[7]?rr[6]:rr[7];
      unsigned long long w03 = w01>w23?w01:w23;
      unsigned long long w47 = w45>w67?w45:w67;
      unsigned long long w   = w03>w47?w03:w47;
      unsigned idx = ~(unsigned)w;
      ax=sm.fps.lx[idx]; ay=sm.fps.ly[idx]; az=sm.fps.lz[idx];
      if(t==0){
        centers[(size_t)(b*3+0)*NS+it]=ax;
        centers[(size_t)(b*3+1)*NS+it]=ay;
        centers[(size_t)(b*3+2)*NS+it]=az;
      }
    }
    return;
  }

  if(blk < ZP_BASE){
    // ---- features (B,128,N) f32 -> point-major (B,N,160) bf16 (channels 0..127) ----
    const int pb = blk - FT_BASE;
    for(int j=0;j<8;++j){
      int tid = pb*8 + j;
      int bb = tid>>7, r = tid&127, ct = r>>6, pt = r&63;
      int c0 = ct*64, p0 = pt*64;
      #pragma unroll
      for(int i=0;i<8;++i){
        int c = (t>>6)*8 + i;
        sm.tile[c][t&63] = features[((size_t)bb*CIN + c0 + c)*NPTS + p0 + (t&63)];
      }
      __syncthreads();
      #pragma unroll
      for(int i=0;i<8;++i){
        int pl = (t>>6)*8 + i;
        featT[((size_t)bb*NPTS + p0 + pl)*C1PAD + c0 + (t&63)] = f2bf(sm.tile[t&63][pl]);
      }
      __syncthreads();
    }
    return;
  }

  if(blk < WP_BASE){
    // ---- zero featT channels 128..159 ----
    const int zb = blk - ZP_BASE;
    s16x8 z = (s16x8){0,0,0,0,0,0,0,0};
    #pragma unroll 4
    for(int i=0;i<32;++i){
      int q = zb*16384 + i*512 + t;
      int bb = q>>14, rem = q&16383, r = rem>>2, c8 = (rem&3)*8;
      *(s16x8*)&featT[((size_t)bb*NPTS + r)*C1PAD + 128 + c8] = z;
    }
    return;
  }

  if(blk < MS_BASE){
    // ---- weight prep into MFMA fragment order (+ zero stats) ----
    int task = (blk - WP_BASE)*512 + t;
    if(task >= 9088) return;
    if(task >= 8704){
      int z = task - 8704;
      if(z < 3*BATCH*8*2) stats[z] = 0.f;
      return;
    }
    int layer, of, cs, ln, ncs; size_t base;
    if(task < 2560){ layer=0; ncs=5; base=0;     int r=task;      of=r/320; r%=320; cs=r>>6; ln=r&63; }
    else if(task < 4608){ layer=1; ncs=4; base=20480; int r=task-2560; of=r>>8; r&=255; cs=r>>6; ln=r&63; }
    else { layer=2; ncs=4; base=36864; int r=task-4608; of=r>>8; r&=255; cs=r>>6; ln=r&63; }
    int o = of*16 + (ln&15);
    s16x8 vals;
    #pragma unroll
    for(int i=0;i<8;++i){
      int c = cs*32 + (ln>>4)*8 + i;
      float v = 0.f;
      if(layer==0){
        if(c<128) v = w1[o*131 + c + 3];
        else if(c<131) v = w1[o*131 + (c-128)];
      } else if(layer==1){
        if(c<128) v = w2[o*128 + c];
      } else {
        if(c<128) v = w3[o*128 + c];
      }
      vals[i]=(short)f2bf(v);
    }
    *(s16x8*)&wfrag[base + ((size_t)(of*ncs + cs)*64 + ln)*8] = vals;
    return;
  }

  {
    // ---- time_emb slice (float4) + style copy ----
    const int mb = blk - MS_BASE;
    #pragma unroll 4
    for(int i=0;i<8;++i){
      int q = mb*4096 + i*512 + t;
      int f = q*4;
      int bb = f>>16, c = (f>>10)&63, s = f&1023;
      *(float4*)&out_time[f] = *(const float4*)&time_emb[((size_t)bb*64 + c)*NPTS + s];
    }
    if(mb==0) out_style[t] = style[t];
  }
}

// ---------------- ball query: one wave per (b,s) ----------------
__global__ __launch_bounds__(256) void k_ballq(const float* __restrict__ coords,
                                               const float* __restrict__ centers,
                                               int* __restrict__ nidx){
  const int gw = (blockIdx.x*256 + threadIdx.x) >> 6;
  const int lane = threadIdx.x & 63;
  const int wl = (threadIdx.x >> 6);
  const int b = gw >> 10, s = gw & (NS-1);
  const float* cb = coords + (size_t)b*3*NPTS;
  const float cx = centers[(size_t)(b*3+0)*NS+s];
  const float cy = centers[(size_t)(b*3+1)*NS+s];
  const float cz = centers[(size_t)(b*3+2)*NS+s];
  __shared__ int slots[4][NK];
  int cnt = 0;
  for(int base=0; base<NPTS && cnt<NK; base+=64){
    int p = base + lane;
    float d2 = exact_d2(cb[p], cb[NPTS+p], cb[2*NPTS+p], cx,cy,cz);
    bool valid = d2 < 0.0225f;
    unsigned long long mask = __ballot(valid);
    int pos = cnt + (int)__popcll(mask & ((1ull<<lane)-1ull));
    if(valid && pos < NK) slots[wl][pos] = p;
    cnt += (int)__popcll(mask);
  }
  __syncthreads();
  int first = slots[wl][0];
  if(lane < NK){
    int v = (lane < cnt) ? slots[wl][lane] : first;
    nidx[((size_t)b*NS + s)*NK + lane] = v;
  }
}

// ---------------- GEMM1: fused gather + 131->128 MFMA + stats ----------------
__global__ __launch_bounds__(256) void k_gemm1(const unsigned short* __restrict__ featT,
    const int* __restrict__ nidx, const float* __restrict__ coords,
    const float* __restrict__ centers, const unsigned short* __restrict__ wfrag,
    const float* __restrict__ bias, unsigned short* __restrict__ yout,
    float* __restrict__ stats){
  const int b=blockIdx.y, mt=blockIdx.x;
  const int m0=mt*64;
  const int t=threadIdx.x, lane=t&63, wid=t>>6;
  __shared__ unsigned short xs[64][168];
  __shared__ unsigned short ys[64][136];
  __shared__ int pidx[64];
  __shared__ float cenS[2][3];
  __shared__ float wsum[2][8][4];
  if(t<64) pidx[t]=nidx[(size_t)b*MTOT + m0 + t];
  if(t>=64 && t<70){ int u=t-64; int j=u/3, c=u%3; cenS[j][c]=centers[((size_t)b*3+c)*NS + (m0>>5)+j]; }
  __syncthreads();
  for(int q=t;q<1280;q+=256){
    int r=q&63, ch=q>>6;
    *(s16x8*)&xs[r][ch*8] = *(const s16x8*)&featT[((size_t)b*NPTS + pidx[r])*C1PAD + ch*8];
  }
  __syncthreads();
  if(t<64){
    int p=pidx[t]; int sj=t>>5;
    float n0=__fadd_rn(coords[((size_t)b*3+0)*NPTS+p],-cenS[sj][0]);
    float n1=__fadd_rn(coords[((size_t)b*3+1)*NPTS+p],-cenS[sj][1]);
    float n2=__fadd_rn(coords[((size_t)b*3+2)*NPTS+p],-cenS[sj][2]);
    s16x4 nc={(short)f2bf(n0),(short)f2bf(n1),(short)f2bf(n2),0};
    *(s16x4*)&xs[t][128]=nc;
  }
  __syncthreads();
  f32x4 acc[8];
  #pragma unroll
  for(int i=0;i<8;++i) acc[i]=(f32x4){0.f,0.f,0.f,0.f};
  const unsigned short* xrow=&xs[wid*16+(lane&15)][0];
  #pragma unroll
  for(int cs=0;cs<5;++cs){
    s16x8 bfv=*(const s16x8*)&xrow[cs*32+(lane>>4)*8];
    #pragma unroll
    for(int of=0;of<8;++of){
      s16x8 afv=*(const s16x8*)&wfrag[((size_t)(of*5+cs)*64+lane)*8];
      acc[of]=__builtin_amdgcn_mfma_f32_16x16x32_bf16(afv,bfv,acc[of],0,0,0);
    }
  }
  #pragma unroll
  for(int of=0;of<8;++of){
    float ls=0.f,lq=0.f;
    int obase=of*16+((lane>>4)<<2);
    #pragma unroll
    for(int r=0;r<4;++r){
      float y=acc[of][r]+bias[obase+r];
      ys[wid*16+(lane&15)][obase+r]=f2bf(y);
      ls+=y; lq+=y*y;
    }
    #pragma unroll
    for(int m=1;m<64;m<<=1){ ls+=__shfl_xor(ls,m); lq+=__shfl_xor(lq,m); }
    if(lane==0){ wsum[0][of][wid]=ls; wsum[1][of][wid]=lq; }
  }
  __syncthreads();
  for(int q=t;q<1024;q+=256){
    int r=q&63, ch=q>>6;
    *(s16x8*)&yout[((size_t)b*MTOT+m0+r)*O1 + ch*8] = *(const s16x8*)&ys[r][ch*8];
  }
  if(t<8){
    float s1v=wsum[0][t][0]+wsum[0][t][1]+wsum[0][t][2]+wsum[0][t][3];
    float s2v=wsum[1][t][0]+wsum[1][t][1]+wsum[1][t][2]+wsum[1][t][3];
    atomicAdd(&stats[((0*BATCH+b)*8+t)*2+0],s1v);
    atomicAdd(&stats[((0*BATCH+b)*8+t)*2+1],s2v);
  }
}

// ---------------- GEMM2/3: stats->norm+SiLU on load, 128->O MFMA + stats ----------------
template<int LAYER>
__global__ __launch_bounds__(256) void k_gemm23(const unsigned short* __restrict__ xin,
    const unsigned short* __restrict__ wfrag, const float* __restrict__ bias,
    const float* __restrict__ stats, const float* __restrict__ gprev,
    const float* __restrict__ beprev, unsigned short* __restrict__ yout,
    float* __restrict__ statsOut){
  const int b=blockIdx.y, mt=blockIdx.x, ot=blockIdx.z;
  const int OTOT=(LAYER==2)?O3:O1;
  const int m0=mt*64;
  const int t=threadIdx.x, lane=t&63, wid=t>>6;
  __shared__ unsigned short xs[64][136];
  __shared__ unsigned short ys[64][136];
  __shared__ float lsc[CIN], lsh[CIN];
  __shared__ float wsum[2][8][4];
  if(t<CIN){
    int g = t>>4;                               // input layer cpg = 16
    const float cnt = 16.0f*NS*NK;
    float s1=stats[(((LAYER-1)*BATCH+b)*8+g)*2+0];
    float s2=stats[(((LAYER-1)*BATCH+b)*8+g)*2+1];
    float mu=s1/cnt, var=s2/cnt-mu*mu;
    float sc=gprev[t]*rsqrtf(var+GN_EPS);
    lsc[t]=sc; lsh[t]=beprev[t]-mu*sc;
  }
  __syncthreads();
  for(int q=t;q<1024;q+=256){
    int r=q&63, ch=q>>6;
    s16x8 v = *(const s16x8*)&xin[((size_t)b*MTOT + m0 + r)*CIN + ch*8];
    s16x8 o;
    #pragma unroll
    for(int i=0;i<8;++i){
      int c=ch*8+i;
      float x = bf2f((unsigned short)v[i]);
      x = x*lsc[c] + lsh[c];
      float sg = 1.0f/(1.0f+__expf(-x));
      o[i]=(short)f2bf(x*sg);
    }
    *(s16x8*)&xs[r][ch*8]=o;
  }
  __syncthreads();
  f32x4 acc[8];
  #pragma unroll
  for(int i=0;i<8;++i) acc[i]=(f32x4){0.f,0.f,0.f,0.f};
  const unsigned short* xrow=&xs[wid*16+(lane&15)][0];
  #pragma unroll
  for(int cs=0;cs<4;++cs){
    s16x8 bfv=*(const s16x8*)&xrow[cs*32+(lane>>4)*8];
    #pragma unroll
    for(int of=0;of<8;++of){
      int ofg=ot*8+of;
      s16x8 afv=*(const s16x8*)&wfrag[((size_t)(ofg*4+cs)*64+lane)*8];
      acc[of]=__builtin_amdgcn_mfma_f32_16x16x32_bf16(afv,bfv,acc[of],0,0,0);
    }
  }
  #pragma unroll
  for(int of=0;of<8;++of){
    float ls=0.f,lq=0.f;
    int lobase=of*16+((lane>>4)<<2);
    int obase=ot*128+lobase;
    #pragma unroll
    for(int r=0;r<4;++r){
      float y=acc[of][r]+bias[obase+r];
      ys[wid*16+(lane&15)][lobase+r]=f2bf(y);
      ls+=y; lq+=y*y;
    }
    #pragma unroll
    for(int m=1;m<64;m<<=1){ ls+=__shfl_xor(ls,m); lq+=__shfl_xor(lq,m); }
    if(lane==0){ wsum[0][of][wid]=ls; wsum[1][of][wid]=lq; }
  }
  __syncthreads();
  for(int q=t;q<1024;q+=256){
    int r=q&63, ch=q>>6;
    *(s16x8*)&yout[((size_t)b*MTOT+m0+r)*OTOT + ot*128 + ch*8] = *(const s16x8*)&ys[r][ch*8];
  }
  if(t<8){
    float s1v=wsum[0][t][0]+wsum[0][t][1]+wsum[0][t][2]+wsum[0][t][3];
    float s2v=wsum[1][t][0]+wsum[1][t][1]+wsum[1][t][2]+wsum[1][t][3];
    int g = (LAYER==2) ? (ot*4 + (t>>1)) : t;
    atomicAdd(&statsOut[((LAYER*BATCH+b)*8+g)*2+0],s1v);
    atomicAdd(&statsOut[((LAYER*BATCH+b)*8+g)*2+1],s2v);
  }
}

// ---------------- final: stats->norm3+SiLU + max over K, transposed coalesced writes ----------------
__global__ __launch_bounds__(256) void k_maxpool(const unsigned short* __restrict__ y3,
    const float* __restrict__ stats, const float* __restrict__ g3,
    const float* __restrict__ be3, float* __restrict__ out){
  const int b = blockIdx.z, st = blockIdx.x, ot = blockIdx.y;
  const int s0 = st*16, o0 = ot*64;
  const int t=threadIdx.x, lane=t&63, wid=t>>6;
  __shared__ float mx[16][68];
  __shared__ float lsc[64], lsh[64];
  if(t<64){
    int c=o0+t, g=c>>5;                         // layer3 cpg = 32
    const float cnt = 32.0f*NS*NK;
    float s1=stats[((2*BATCH+b)*8+g)*2+0];
    float s2=stats[((2*BATCH+b)*8+g)*2+1];
    float mu=s1/cnt, var=s2/cnt-mu*mu;
    float sc=g3[c]*rsqrtf(var+GN_EPS);
    lsc[t]=sc; lsh[t]=be3[c]-mu*sc;
  }
  __syncthreads();
  for(int si=wid; si<16; si+=4){
    int s = s0+si;
    float m = -3.4e38f;
    float sc=lsc[lane], sh=lsh[lane];
    for(int k=0;k<NK;++k){
      float v = bf2f(y3[((size_t)b*MTOT + s*NK + k)*O3 + o0 + lane]);
      v = v*sc + sh;
      float sg = 1.0f/(1.0f+__expf(-v));
      v = v*sg;
      m = fmaxf(m,v);
    }
    mx[si][lane] = m;
  }
  __syncthreads();
  {
    int ol = t>>2, sl = (t&3)*4;
    float4 v = make_float4(mx[sl][ol], mx[sl+1][ol], mx[sl+2][ol], mx[sl+3][ol]);
    *(float4*)&out[((size_t)(b*O3 + o0+ol))*NS + s0 + sl] = v;
  }
}

extern "C" void kernel_launch(void* const* d_in, const int* in_sizes, int n_in,
                              void* d_out, int out_size, void* d_ws, size_t ws_size,
                              hipStream_t stream){
  const float* features=(const float*)d_in[0];
  const float* coords=(const float*)d_in[1];
  const float* time_emb=(const float*)d_in[2];
  const float* style=(const float*)d_in[3];
  const float* w1=(const float*)d_in[4];
  const float* b1=(const float*)d_in[5];
  const float* g1=(const float*)d_in[6];
  const float* be1=(const float*)d_in[7];
  const float* w2=(const float*)d_in[8];
  const float* b2=(const float*)d_in[9];
  const float* g2=(const float*)d_in[10];
  const float* be2=(const float*)d_in[11];
  const float* w3=(const float*)d_in[12];
  const float* b3=(const float*)d_in[13];
  const float* g3=(const float*)d_in[14];
  const float* be3=(const float*)d_in[15];

  float* out0=(float*)d_out;
  float* out_centers=out0 + (size_t)BATCH*O3*NS;
  float* out_time=out_centers + (size_t)BATCH*3*NS;
  float* out_style=out_time + (size_t)BATCH*64*NS;

  char* ws=(char*)d_ws;
  int* nidx=(int*)(ws + 131072);
  unsigned short* featT=(unsigned short*)(ws + 1179648);
  unsigned short* wfrag=(unsigned short*)(ws + 11796480);
  float* stats=(float*)(ws + 11939840);
  unsigned short* y3=(unsigned short*)(ws + 12582912);   // 128 MB region; y1 aliases first half
  unsigned short* y1=y3;
  unsigned short* y2=(unsigned short*)(ws + 146800640);  // 64 MB

  k_fused<<<TOTAL_BLOCKS,512,0,stream>>>(coords,features,time_emb,style,w1,w2,w3,
                                         out_centers,out_time,out_style,featT,wfrag,stats);
  k_ballq<<<2048,256,0,stream>>>(coords,out_centers,nidx);
  k_gemm1<<<dim3(512,BATCH),256,0,stream>>>(featT,nidx,coords,out_centers,wfrag,b1,y1,stats);
  k_gemm23<1><<<dim3(512,BATCH,1),256,0,stream>>>(y1,wfrag+20480,b2,stats,g1,be1,y2,stats);
  k_gemm23<2><<<dim3(512,BATCH,2),256,0,stream>>>(y2,wfrag+36864,b3,stats,g2,be2,y3,stats);
  k_maxpool<<<dim3(64,4,BATCH),256,0,stream>>>(y3,stats,g3,be3,out0);
}